// Round 9
// baseline (1424.088 us; speedup 1.0000x reference)
//
#include <hip/hip_runtime.h>
#include <math.h>

typedef unsigned short u16;
typedef short s16x8 __attribute__((ext_vector_type(8)));
typedef float f32x16 __attribute__((ext_vector_type(16)));

#define GLOAD16(gp, lp)                                                        \
  __builtin_amdgcn_global_load_lds(                                            \
      (const __attribute__((address_space(1))) void*)(gp),                     \
      (__attribute__((address_space(3))) void*)(lp), 16, 0, 0)

__device__ __forceinline__ u16 f2bf(float f) {
  union { float f; unsigned u; } v; v.f = f;
  unsigned r = v.u + 0x7fffu + ((v.u >> 16) & 1u);  // RNE
  return (u16)(r >> 16);
}

// ---------------- kernel 1: x fp32 -> bf16 ----------------
__global__ __launch_bounds__(256) void cvt_x_kernel(const float* __restrict__ in,
                                                    u16* __restrict__ out) {
  size_t i = ((size_t)blockIdx.x * 256 + threadIdx.x) * 8;
  float4 a = *(const float4*)(in + i);
  float4 b = *(const float4*)(in + i + 4);
  s16x8 v;
  v[0] = (short)f2bf(a.x); v[1] = (short)f2bf(a.y);
  v[2] = (short)f2bf(a.z); v[3] = (short)f2bf(a.w);
  v[4] = (short)f2bf(b.x); v[5] = (short)f2bf(b.y);
  v[6] = (short)f2bf(b.z); v[7] = (short)f2bf(b.w);
  *(s16x8*)(out + i) = v;
}

// ------- kernel 2: transpose+cvt. mats 0-3 (g/u) -> interleaved GU with
// 128-row blocking: GU row = (f>>7)*256 + t*128 + (f&127), t=0 gate, 1 up.
// mats 4,5 plain transpose.
__global__ __launch_bounds__(256) void transpose_cvt_kernel(
    const float* __restrict__ in0, const float* __restrict__ in1,
    const float* __restrict__ in2, const float* __restrict__ in3,
    const float* __restrict__ in4, const float* __restrict__ in5,
    u16* __restrict__ o01, u16* __restrict__ o23,
    u16* __restrict__ o4, u16* __restrict__ o5) {
  __shared__ float s[64 * 65];
  const int mat = blockIdx.y;
  const float* in; u16* out;
  switch (mat) {
    case 0: in = in0; out = o01; break;
    case 1: in = in1; out = o01; break;
    case 2: in = in2; out = o23; break;
    case 3: in = in3; out = o23; break;
    case 4: in = in4; out = o4; break;
    default: in = in5; out = o5; break;
  }
  const int R = (mat < 4) ? 4096 : 11008;
  const int C = (mat < 4) ? 11008 : 4096;
  const int nTc = C >> 6;
  const int tr = blockIdx.x / nTc, tc = blockIdx.x - tr * nTc;
  const int r0 = tr << 6, c0 = tc << 6;
  const int t = threadIdx.x;
#pragma unroll
  for (int p = 0; p < 4; ++p) {
    const int lr = p * 16 + (t >> 4);
    const int lc = (t & 15) * 4;
    float4 v = *(const float4*)(in + (size_t)(r0 + lr) * C + (c0 + lc));
    float* sp = &s[lr * 65 + lc];
    sp[0] = v.x; sp[1] = v.y; sp[2] = v.z; sp[3] = v.w;
  }
  __syncthreads();
#pragma unroll
  for (int q = 0; q < 2; ++q) {
    const int oc = q * 32 + (t >> 3);
    const int orr = (t & 7) * 8;
    s16x8 v;
#pragma unroll
    for (int i = 0; i < 8; ++i) v[i] = (short)f2bf(s[(orr + i) * 65 + oc]);
    const int f = c0 + oc;
    size_t orow;
    if (mat < 4) orow = (size_t)((f >> 7) << 8) + ((mat & 1) << 7) + (f & 127);
    else         orow = (size_t)f;
    *(s16x8*)(out + orow * R + (r0 + orr)) = v;
  }
}

// ======== 256x256 GEMM core: 32x32x16 MFMA, 8-phase 2-barrier (R7 core) =====
// 8 waves (2M x 4N). Frag-once ds_reads; bf[2] n-sets resident P1..P4.
// LDS [2buf][2half][128][64] u16/operand; swizzle chunk = logical ^ (r&7) ^
// ((r>>3)&3) (pre-swizzled global src + read addr) — verified 0 conflicts (R7).
// Per 2 K-tiles (8 phases): reads P1{af(mh0),bf0} P2{bf1} P3{af(mh1)} P4{}
// (mirror P5-P8 on buf1); stages 1 half/phase: A1'(T+1)@P1, A0'(T+2)@P2,
// B0'@P3, B1'@P4, A1'(T+2)@P5, A0'(T+3)@P6, B0'@P7, B1'@P8; vmcnt(6)@P4/P8.
#define SBAR() __builtin_amdgcn_s_barrier()
#define LGKM0() asm volatile("s_waitcnt lgkmcnt(0)")
#define LGKM8() asm volatile("s_waitcnt lgkmcnt(8)")
#define VMCNT6() asm volatile("s_waitcnt vmcnt(6)")
#define VMCNT0() asm volatile("s_waitcnt vmcnt(0)")

#define LDA(d, mh)                                                             \
  do {                                                                         \
    _Pragma("unroll") for (int fj = 0; fj < 2; ++fj)                           \
        _Pragma("unroll") for (int ks = 0; ks < 4; ++ks)                       \
        af[fj][ks] = *(const s16x8*)(ldsA + (d) * 32768 + (mh) * 16384 +       \
                                     arow + fj * 4096 + cx[ks]);               \
  } while (0)
#define LDB(d, nh)                                                             \
  do {                                                                         \
    _Pragma("unroll") for (int ks = 0; ks < 4; ++ks)                           \
        bf[nh][ks] = *(const s16x8*)(ldsB + (d) * 32768 + (nh) * 16384 +       \
                                     brow + cx[ks]);                           \
  } while (0)
#define MFMA8(mh, nh)                                                          \
  do {                                                                         \
    __builtin_amdgcn_s_setprio(1);                                             \
    _Pragma("unroll") for (int fj = 0; fj < 2; ++fj)                           \
        _Pragma("unroll") for (int ks = 0; ks < 4; ++ks)                       \
        acc[mh][fj][nh] = __builtin_amdgcn_mfma_f32_32x32x16_bf16(             \
            af[fj][ks], bf[nh][ks], acc[mh][fj][nh], 0, 0, 0);                 \
    __builtin_amdgcn_s_setprio(0);                                             \
  } while (0)

// Generic 8-phase pipeline; STG_A/STG_B kernel-local (q = flat K-tile idx).
// HOOK runs after P8's closing barrier of each 2-K-tile pair.
#define GEMM_PIPE8(FKv, HOOK)                                                  \
  do {                                                                         \
    STG_A(0, 0, 0); STG_B(0, 0, 0); STG_B(0, 1, 0); STG_A(0, 1, 0);            \
    STG_A(1, 0, 1); STG_B(1, 0, 1); STG_B(1, 1, 1);                            \
    VMCNT6(); SBAR();                                                          \
    for (int T = 0; T < (FKv)-2; T += 2) {                                     \
      LDA(0, 0); LDB(0, 0);                                                    \
      STG_A(1, 1, T + 1);                                                      \
      LGKM8();                                                                 \
      SBAR(); LGKM0(); MFMA8(0, 0); SBAR();                                    \
      LDB(0, 1);                                                               \
      STG_A(0, 0, T + 2);                                                      \
      SBAR(); LGKM0(); MFMA8(0, 1); SBAR();                                    \
      LDA(0, 1);                                                               \
      STG_B(0, 0, T + 2);                                                      \
      SBAR(); LGKM0(); MFMA8(1, 1); SBAR();                                    \
      STG_B(0, 1, T + 2);                                                      \
      VMCNT6();                                                                \
      SBAR(); MFMA8(1, 0); SBAR();                                             \
      LDA(1, 0); LDB(1, 0);                                                    \
      STG_A(0, 1, T + 2);                                                      \
      LGKM8();                                                                 \
      SBAR(); LGKM0(); MFMA8(0, 0); SBAR();                                    \
      LDB(1, 1);                                                               \
      STG_A(1, 0, T + 3);                                                      \
      SBAR(); LGKM0(); MFMA8(0, 1); SBAR();                                    \
      LDA(1, 1);                                                               \
      STG_B(1, 0, T + 3);                                                      \
      SBAR(); LGKM0(); MFMA8(1, 1); SBAR();                                    \
      STG_B(1, 1, T + 3);                                                      \
      VMCNT6();                                                                \
      SBAR(); MFMA8(1, 0); SBAR();                                             \
      HOOK;                                                                    \
    }                                                                          \
    LDA(0, 0); LDB(0, 0);                                                      \
    STG_A(1, 1, (FKv)-1);                                                      \
    LGKM8();                                                                   \
    SBAR(); LGKM0(); MFMA8(0, 0); SBAR();                                      \
    LDB(0, 1);                                                                 \
    SBAR(); LGKM0(); MFMA8(0, 1); SBAR();                                      \
    LDA(0, 1);                                                                 \
    SBAR(); LGKM0(); MFMA8(1, 1); SBAR();                                      \
    VMCNT0();                                                                  \
    SBAR(); MFMA8(1, 0); SBAR();                                               \
    LDA(1, 0); LDB(1, 0);                                                      \
    LGKM8();                                                                   \
    SBAR(); LGKM0(); MFMA8(0, 0); SBAR();                                      \
    LDB(1, 1);                                                                 \
    SBAR(); LGKM0(); MFMA8(0, 1); SBAR();                                      \
    LDA(1, 1);                                                                 \
    SBAR(); LGKM0(); MFMA8(1, 1); SBAR();                                      \
    MFMA8(1, 0);                                                               \
  } while (0)

#define ZERO_ACC()                                                             \
  do {                                                                         \
    _Pragma("unroll") for (int a = 0; a < 2; ++a)                              \
        _Pragma("unroll") for (int b = 0; b < 2; ++b)                          \
        _Pragma("unroll") for (int c2 = 0; c2 < 2; ++c2)                       \
        _Pragma("unroll") for (int r = 0; r < 16; ++r) acc[a][b][c2][r] = 0.f; \
  } while (0)

// ---------------- persistent gate+up GEMM + silu (static XCD-aligned) -------
// c-lane = ((bid>>7)<<3)|(bid&7): the 16 blocks sharing a B-panel all have the
// same bid%8 -> same XCD -> B fetched ~once per XCD L2. mT pinned per block ->
// A-panel L2-resident. Seamless flat-K walk over ntiles tiles (nT = c + 16*j),
// epilogue hook inside the pipeline (prefetch of next tile stays in flight).
__global__ __launch_bounds__(512, 1) void gemm_gateup_persist(
    const u16* __restrict__ A, const u16* __restrict__ GUl,
    const u16* __restrict__ GUv, const int* __restrict__ tt,
    u16* __restrict__ H) {
  __shared__ u16 sA[2][2][128][64];
  __shared__ u16 sB[2][2][128][64];

  const int bid = blockIdx.x;
  const int c = ((bid >> 7) << 3) | (bid & 7);
  const int mT = (bid >> 3) & 15;
  const int ntiles = (c < 6) ? 6 : 5;
  const int FK = ntiles * 64;

  const int t = threadIdx.x;
  const int lane = t & 63;
  const int l31 = lane & 31;
  const int kg = lane >> 5;
  const int wn = (t >> 6) & 3;
  const int wm = (t >> 8) & 1;

  const int side = tt[mT << 8];
  const u16* GU = side ? GUl : GUv;

  const int rowq = t >> 3;
  const int gsw = ((t & 7) ^ (rowq & 7) ^ ((rowq >> 3) & 3)) << 4;
  const char* srcA = (const char*)A + (size_t)(mT * 256 + rowq) * 8192 + gsw;
  const char* srcB0 = (const char*)GU + ((size_t)(c * 256) + rowq) * 8192 + gsw;
  char* ldsA = (char*)&sA[0][0][0][0];
  char* ldsB = (char*)&sB[0][0][0][0];
  const int woff = (t & 448) << 4;

#define STG_A(d, h, q)                                                         \
  do {                                                                         \
    const char* _pa = srcA + ((q)&63) * 128;                                   \
    GLOAD16(_pa + (size_t)((h)*128) * 8192,                                    \
            ldsA + (d)*32768 + (h)*16384 + woff);                              \
    GLOAD16(_pa + (size_t)((h)*128 + 64) * 8192,                               \
            ldsA + (d)*32768 + (h)*16384 + 8192 + woff);                       \
  } while (0)
#define STG_B(d, h, q)                                                         \
  do {                                                                         \
    const char* _pb = srcB0 + (size_t)((q) >> 6) * 33554432 +                  \
                      (size_t)((h)*128) * 8192 + ((q)&63) * 128;               \
    GLOAD16(_pb, ldsB + (d)*32768 + (h)*16384 + woff);                         \
    GLOAD16(_pb + (size_t)64 * 8192,                                           \
            ldsB + (d)*32768 + (h)*16384 + 8192 + woff);                       \
  } while (0)

  const int arow = (wm * 64 + l31) * 128;
  const int brow = (wn * 32 + l31) * 128;
  int cx[4];
#pragma unroll
  for (int ks = 0; ks < 4; ++ks)
    cx[ks] = ((2 * ks + kg) ^ (l31 & 7) ^ ((l31 >> 3) & 3)) << 4;

  s16x8 af[2][4], bf[2][4];
  f32x16 acc[2][2][2];
  ZERO_ACC();

#define GU_EPI(nTv)                                                            \
  do {                                                                         \
    const int _nT = (nTv);                                                     \
    const int f = _nT * 128 + wn * 32 + l31;                                   \
    _Pragma("unroll") for (int mh = 0; mh < 2; ++mh)                           \
        _Pragma("unroll") for (int fj = 0; fj < 2; ++fj) {                     \
      const int rowbase = mT * 256 + mh * 128 + wm * 64 + fj * 32 + 4 * kg;    \
      _Pragma("unroll") for (int r = 0; r < 16; ++r) {                         \
        const int row = rowbase + (r & 3) + 8 * (r >> 2);                      \
        const float gv = acc[mh][fj][0][r];                                    \
        const float uv = acc[mh][fj][1][r];                                    \
        const float hv = gv / (1.f + __expf(-gv)) * uv;                        \
        H[(size_t)row * 11008 + f] = f2bf(hv);                                 \
      }                                                                        \
    }                                                                          \
  } while (0)

  GEMM_PIPE8(FK, if ((T & 63) == 62) { GU_EPI(c + 16 * (T >> 6)); ZERO_ACC(); });
  GU_EPI(c + 16 * (ntiles - 1));
#undef STG_A
#undef STG_B
#undef GU_EPI
}

// ---------------- down GEMM (static 1 tile/block, 8-phase core) -------------
__global__ __launch_bounds__(512, 1) void gemm_down(
    const u16* __restrict__ Hm, const u16* __restrict__ Dl,
    const u16* __restrict__ Dv, const int* __restrict__ tt,
    float* __restrict__ O) {
  constexpr int KB = 22016;  // bytes per K-row
  __shared__ u16 sA[2][2][128][64];
  __shared__ u16 sB[2][2][128][64];

  const int bid = blockIdx.x;
  const int wg = (bid & 7) * 32 + (bid >> 3);  // bijective XCD swizzle
  const int mT = wg & 15;
  const int nT = wg >> 4;

  const int t = threadIdx.x;
  const int lane = t & 63;
  const int l31 = lane & 31;
  const int kg = lane >> 5;
  const int wn = (t >> 6) & 3;
  const int wm = (t >> 8) & 1;

  const int side = tt[mT << 8];
  const u16* B = side ? Dl : Dv;

  const int rowq = t >> 3;
  const int gsw = ((t & 7) ^ (rowq & 7) ^ ((rowq >> 3) & 3)) << 4;
  const char* srcA = (const char*)Hm + (size_t)(mT * 256 + rowq) * KB + gsw;
  const char* srcB = (const char*)B + (size_t)(nT * 256 + rowq) * KB + gsw;
  char* ldsA = (char*)&sA[0][0][0][0];
  char* ldsB = (char*)&sB[0][0][0][0];
  const int woff = (t & 448) << 4;

#define STG_A(d, h, q)                                                         \
  do {                                                                         \
    GLOAD16(srcA + (size_t)((h)*128) * KB + (size_t)(q)*128,                   \
            ldsA + (d)*32768 + (h)*16384 + woff);                              \
    GLOAD16(srcA + (size_t)((h)*128 + 64) * KB + (size_t)(q)*128,              \
            ldsA + (d)*32768 + (h)*16384 + 8192 + woff);                       \
  } while (0)
#define STG_B(d, h, q)                                                         \
  do {                                                                         \
    GLOAD16(srcB + (size_t)((h)*128) * KB + (size_t)(q)*128,                   \
            ldsB + (d)*32768 + (h)*16384 + woff);                              \
    GLOAD16(srcB + (size_t)((h)*128 + 64) * KB + (size_t)(q)*128,              \
            ldsB + (d)*32768 + (h)*16384 + 8192 + woff);                       \
  } while (0)

  const int arow = (wm * 64 + l31) * 128;
  const int brow = (wn * 32 + l31) * 128;
  int cx[4];
#pragma unroll
  for (int ks = 0; ks < 4; ++ks)
    cx[ks] = ((2 * ks + kg) ^ (l31 & 7) ^ ((l31 >> 3) & 3)) << 4;

  s16x8 af[2][4], bf[2][4];
  f32x16 acc[2][2][2];
  ZERO_ACC();

  GEMM_PIPE8(172, ;);

#pragma unroll
  for (int mh = 0; mh < 2; ++mh)
#pragma unroll
    for (int fj = 0; fj < 2; ++fj) {
      const int rowbase = mT * 256 + mh * 128 + wm * 64 + fj * 32 + 4 * kg;
#pragma unroll
      for (int nh = 0; nh < 2; ++nh) {
        const int col = nT * 256 + nh * 128 + wn * 32 + l31;
#pragma unroll
        for (int r = 0; r < 16; ++r) {
          const int row = rowbase + (r & 3) + 8 * (r >> 2);
          O[(size_t)row * 4096 + col] = acc[mh][fj][nh][r];
        }
      }
    }
#undef STG_A
#undef STG_B
}

extern "C" void kernel_launch(void* const* d_in, const int* in_sizes, int n_in,
                              void* d_out, int out_size, void* d_ws, size_t ws_size,
                              hipStream_t stream) {
  (void)in_sizes; (void)n_in; (void)out_size; (void)ws_size;
  const float* x  = (const float*)d_in[0];
  const int*   tt = (const int*)d_in[1];
  const float* lg = (const float*)d_in[2];
  const float* lu = (const float*)d_in[3];
  const float* ld = (const float*)d_in[4];
  const float* vg = (const float*)d_in[5];
  const float* vu = (const float*)d_in[6];
  const float* vd = (const float*)d_in[7];

  u16* ws  = (u16*)d_ws;
  u16* xbf = ws;                        // 4096*4096            = 16,777,216
  u16* GUl = xbf + 16777216;            // 22016*4096           = 90,177,536
  u16* GUv = GUl + 90177536;
  u16* ldT = GUv + 90177536;            // 4096*11008           = 45,088,768
  u16* vdT = ldT + 45088768;
  u16* hbuf = vdT + 45088768;           // 4096*11008
  // total: 332,398,592 u16 = ~665 MB

  cvt_x_kernel<<<dim3(8192), dim3(256), 0, stream>>>(x, xbf);
  transpose_cvt_kernel<<<dim3(11008, 6), dim3(256), 0, stream>>>(
      lg, lu, vg, vu, ld, vd, GUl, GUv, ldT, vdT);
  gemm_gateup_persist<<<dim3(256), dim3(512), 0, stream>>>(
      xbf, GUl, GUv, tt, hbuf);
  gemm_down<<<dim3(256), dim3(512), 0, stream>>>(hbuf, ldT, vdT, tt, (float*)d_out);
}

// Round 10
// 1304.270 us; speedup vs baseline: 1.0919x; 1.0919x over previous
//
#include <hip/hip_runtime.h>
#include <math.h>

typedef unsigned short u16;
typedef short s16x8 __attribute__((ext_vector_type(8)));
typedef float f32x4 __attribute__((ext_vector_type(4)));

#define GLOAD16(gp, lp)                                                        \
  __builtin_amdgcn_global_load_lds(                                            \
      (const __attribute__((address_space(1))) void*)(gp),                     \
      (__attribute__((address_space(3))) void*)(lp), 16, 0, 0)

__device__ __forceinline__ u16 f2bf(float f) {
  union { float f; unsigned u; } v; v.f = f;
  unsigned r = v.u + 0x7fffu + ((v.u >> 16) & 1u);  // RNE
  return (u16)(r >> 16);
}

// ------- kernel A: transpose+cvt (y=0..5) + x cvt (y=6).
// mats 0-3 (g/u) write into interleaved GU: row = (f>>4)*32 + t*16 + (f&15).
// mats 4,5 plain transpose. y=6: x fp32->bf16 flat copy (blocks 0..8191).
__global__ __launch_bounds__(256) void prep_kernel(
    const float* __restrict__ in0, const float* __restrict__ in1,
    const float* __restrict__ in2, const float* __restrict__ in3,
    const float* __restrict__ in4, const float* __restrict__ in5,
    const float* __restrict__ xin,
    u16* __restrict__ o01, u16* __restrict__ o23,
    u16* __restrict__ o4, u16* __restrict__ o5, u16* __restrict__ xout) {
  const int mat = blockIdx.y;
  const int t = threadIdx.x;
  if (mat == 6) {  // x conversion: 8192 blocks x 2048 elems
    if (blockIdx.x >= 8192) return;
    size_t i = ((size_t)blockIdx.x * 256 + t) * 8;
    float4 a = *(const float4*)(xin + i);
    float4 b = *(const float4*)(xin + i + 4);
    s16x8 v;
    v[0] = (short)f2bf(a.x); v[1] = (short)f2bf(a.y);
    v[2] = (short)f2bf(a.z); v[3] = (short)f2bf(a.w);
    v[4] = (short)f2bf(b.x); v[5] = (short)f2bf(b.y);
    v[6] = (short)f2bf(b.z); v[7] = (short)f2bf(b.w);
    *(s16x8*)(xout + i) = v;
    return;
  }
  __shared__ float s[64 * 65];
  const float* in; u16* out;
  switch (mat) {
    case 0: in = in0; out = o01; break;
    case 1: in = in1; out = o01; break;
    case 2: in = in2; out = o23; break;
    case 3: in = in3; out = o23; break;
    case 4: in = in4; out = o4; break;
    default: in = in5; out = o5; break;
  }
  const int R = (mat < 4) ? 4096 : 11008;   // input rows = output stride
  const int C = (mat < 4) ? 11008 : 4096;   // input cols
  const int nTc = C >> 6;
  const int tr = blockIdx.x / nTc, tc = blockIdx.x - tr * nTc;
  const int r0 = tr << 6, c0 = tc << 6;
#pragma unroll
  for (int p = 0; p < 4; ++p) {
    const int lr = p * 16 + (t >> 4);
    const int lc = (t & 15) * 4;
    float4 v = *(const float4*)(in + (size_t)(r0 + lr) * C + (c0 + lc));
    float* sp = &s[lr * 65 + lc];
    sp[0] = v.x; sp[1] = v.y; sp[2] = v.z; sp[3] = v.w;
  }
  __syncthreads();
#pragma unroll
  for (int q = 0; q < 2; ++q) {
    const int oc = q * 32 + (t >> 3);
    const int orr = (t & 7) * 8;
    s16x8 v;
#pragma unroll
    for (int i = 0; i < 8; ++i) v[i] = (short)f2bf(s[(orr + i) * 65 + oc]);
    const int f = c0 + oc;
    size_t orow;
    if (mat < 4) orow = (size_t)((f >> 4) << 5) + ((mat & 1) << 4) + (f & 15);
    else         orow = (size_t)f;
    *(s16x8*)(out + orow * R + (r0 + orr)) = v;
  }
}

// ======== 8-phase 256x256 GEMM, frag-once schedule (R5 core, verified) ======
// Quadrants (0,0)(0,1)(1,1)(1,0); bf[2 nh-sets] resident -> each fragment is
// ds_read exactly ONCE (48 b128/iter/wave). Stage order satisfies
// stage-after-last-read: reads buf0 {A0,B0}@P1 {B1}@P2 {A1}@P3, stages
// A-h1(T+1)@P1, A-h0(T+2)@P2, B-h0@P3, B-h1@P4, A-h1@P5; buf1 mirrored P5-P8
// + next-P1. vmcnt(6) at P4/P8 drains everything except the newest 3 halves.
#define SBAR() __builtin_amdgcn_s_barrier()
#define LGKM0() asm volatile("s_waitcnt lgkmcnt(0)")
#define LGKM8() asm volatile("s_waitcnt lgkmcnt(8)")
#define VMCNT6() asm volatile("s_waitcnt vmcnt(6)")
#define VMCNT0() asm volatile("s_waitcnt vmcnt(0)")

// ---------------- persistent gate+up GEMM + silu fusion ----------------
__global__ __launch_bounds__(512, 1) void gemm_gateup_persist(
    const u16* __restrict__ A, const u16* __restrict__ Bl,
    const u16* __restrict__ Bv, const int* __restrict__ tt,
    u16* __restrict__ H) {
  __shared__ u16 sA[2][2][128][64];
  __shared__ u16 sB[2][2][128][64];

  const int bid = blockIdx.x;
  const int c = ((bid >> 7) << 3) | (bid & 7);
  const int mT = (bid >> 3) & 15;
  const int ntiles = (c < 6) ? 6 : 5;
  const int FK = ntiles * 64;

  const int t = threadIdx.x;
  const int lane = t & 63;
  const int rlo = lane & 15;
  const int hi = lane >> 4;
  const int wn = (t >> 6) & 3;
  const int wm = (t >> 8) & 1;

  const int side = tt[mT << 8];
  const u16* B = side ? Bl : Bv;

  const int rowq = t >> 3;
  const int gsw = ((t & 7) ^ (rowq & 7)) << 4;
  const char* srcA = (const char*)A + (size_t)(mT * 256 + rowq) * 8192 + gsw;
  const char* srcB0 = (const char*)B + ((size_t)(c * 256) + rowq) * 8192 + gsw;
  char* ldsA = (char*)&sA[0][0][0][0];
  char* ldsB = (char*)&sB[0][0][0][0];
  const int woff = (t & 448) << 4;

#define PSTG_A(d, h, q)                                                        \
  do {                                                                         \
    const char* _pa = srcA + ((q) & 63) * 128;                                 \
    GLOAD16(_pa + (size_t)((h) * 128) * 8192,                                  \
            ldsA + (d) * 32768 + (h) * 16384 + woff);                          \
    GLOAD16(_pa + (size_t)((h) * 128 + 64) * 8192,                             \
            ldsA + (d) * 32768 + (h) * 16384 + 8192 + woff);                   \
  } while (0)
#define PSTG_B(d, h, q)                                                        \
  do {                                                                         \
    const char* _pb = srcB0 + (size_t)((q) >> 6) * 33554432 +                  \
                      (size_t)((h) * 128) * 8192 + ((q) & 63) * 128;           \
    GLOAD16(_pb, ldsB + (d) * 32768 + (h) * 16384 + woff);                     \
    GLOAD16(_pb + (size_t)64 * 8192,                                           \
            ldsB + (d) * 32768 + (h) * 16384 + 8192 + woff);                   \
  } while (0)

  const int cxa = (hi ^ (rlo & 7)) << 4;
  const int cxb = ((4 + hi) ^ (rlo & 7)) << 4;
  const int arow = (wm * 64 + rlo) * 128;
  const int brow = (wn * 32 + rlo) * 128;

  s16x8 af[4][2], bf[2][2][2];  // bf[nh-set][gi][ks] resident across P1..P4
  f32x4 acc[8][4];
  const f32x4 z = {0.f, 0.f, 0.f, 0.f};
#pragma unroll
  for (int i = 0; i < 8; ++i)
#pragma unroll
    for (int j = 0; j < 4; ++j) acc[i][j] = z;

#define LDA(d, mh)                                                             \
  do {                                                                         \
    _Pragma("unroll") for (int fi = 0; fi < 4; ++fi) {                         \
      const char* p = ldsA + (d) * 32768 + (mh) * 16384 + arow + fi * 2048;    \
      af[fi][0] = *(const s16x8*)(p + cxa);                                    \
      af[fi][1] = *(const s16x8*)(p + cxb);                                    \
    }                                                                          \
  } while (0)
#define LDBS(bi, d, nh)                                                        \
  do {                                                                         \
    _Pragma("unroll") for (int gi = 0; gi < 2; ++gi) {                         \
      const char* p = ldsB + (d) * 32768 + (nh) * 16384 + brow + gi * 2048;    \
      bf[bi][gi][0] = *(const s16x8*)(p + cxa);                                \
      bf[bi][gi][1] = *(const s16x8*)(p + cxb);                                \
    }                                                                          \
  } while (0)
#define MFMA16(mh, nh)                                                         \
  do {                                                                         \
    __builtin_amdgcn_s_setprio(1);                                             \
    _Pragma("unroll") for (int fi = 0; fi < 4; ++fi)                           \
        _Pragma("unroll") for (int gi = 0; gi < 2; ++gi) {                     \
      acc[(mh)*4 + fi][(nh)*2 + gi] = __builtin_amdgcn_mfma_f32_16x16x32_bf16( \
          af[fi][0], bf[nh][gi][0], acc[(mh)*4 + fi][(nh)*2 + gi], 0, 0, 0);   \
      acc[(mh)*4 + fi][(nh)*2 + gi] = __builtin_amdgcn_mfma_f32_16x16x32_bf16( \
          af[fi][1], bf[nh][gi][1], acc[(mh)*4 + fi][(nh)*2 + gi], 0, 0, 0);   \
    }                                                                          \
    __builtin_amdgcn_s_setprio(0);                                             \
  } while (0)

#define GU_EPI(nTv)                                                            \
  do {                                                                         \
    const int _nT = (nTv);                                                     \
    _Pragma("unroll") for (int mh = 0; mh < 2; ++mh)                           \
        _Pragma("unroll") for (int fi = 0; fi < 4; ++fi) {                     \
      const int row0 = mT * 256 + mh * 128 + wm * 64 + fi * 16 + hi * 4;       \
      _Pragma("unroll") for (int nh = 0; nh < 2; ++nh) {                       \
        const int fc = _nT * 128 + (nh * 4 + wn) * 16 + rlo;                   \
        const f32x4 g = acc[mh * 4 + fi][nh * 2 + 0];                          \
        const f32x4 u = acc[mh * 4 + fi][nh * 2 + 1];                          \
        _Pragma("unroll") for (int r = 0; r < 4; ++r) {                        \
          const float gv = g[r];                                               \
          const float hv = gv / (1.f + __expf(-gv)) * u[r];                    \
          H[(size_t)(row0 + r) * 11008 + fc] = f2bf(hv);                       \
        }                                                                      \
      }                                                                        \
    }                                                                          \
  } while (0)

  // prologue: tile0 full -> buf0; tile1 {A-h0, B-h0, B-h1} -> buf1
  PSTG_A(0, 0, 0); PSTG_B(0, 0, 0); PSTG_B(0, 1, 0); PSTG_A(0, 1, 0);
  PSTG_A(1, 0, 1); PSTG_B(1, 0, 1); PSTG_B(1, 1, 1);
  VMCNT6();
  SBAR();

  for (int T = 0; T < FK - 2; T += 2) {
    // P1: af(mh0), bf0 | stage A-h1(T+1)->buf1
    LDA(0, 0); LDBS(0, 0, 0);
    PSTG_A(1, 1, T + 1);
    LGKM8();
    SBAR(); LGKM0(); MFMA16(0, 0); SBAR();
    // P2: bf1 | stage A-h0(T+2)->buf0
    LDBS(1, 0, 1);
    PSTG_A(0, 0, T + 2);
    SBAR(); LGKM0(); MFMA16(0, 1); SBAR();
    // P3: af(mh1) | stage B-h0(T+2)->buf0
    LDA(0, 1);
    PSTG_B(0, 0, T + 2);
    SBAR(); LGKM0(); MFMA16(1, 1); SBAR();
    // P4: no reads | stage B-h1(T+2)->buf0 | checkpoint
    PSTG_B(0, 1, T + 2);
    VMCNT6();
    SBAR(); MFMA16(1, 0); SBAR();
    // P5: buf1 af(mh0), bf0 | stage A-h1(T+2)->buf0
    LDA(1, 0); LDBS(0, 1, 0);
    PSTG_A(0, 1, T + 2);
    LGKM8();
    SBAR(); LGKM0(); MFMA16(0, 0); SBAR();
    // P6: bf1 | stage A-h0(T+3)->buf1
    LDBS(1, 1, 1);
    PSTG_A(1, 0, T + 3);
    SBAR(); LGKM0(); MFMA16(0, 1); SBAR();
    // P7: af(mh1) | stage B-h0(T+3)->buf1
    LDA(1, 1);
    PSTG_B(1, 0, T + 3);
    SBAR(); LGKM0(); MFMA16(1, 1); SBAR();
    // P8: no reads | stage B-h1(T+3)->buf1 | checkpoint
    PSTG_B(1, 1, T + 3);
    VMCNT6();
    SBAR(); MFMA16(1, 0); SBAR();

    if ((T & 63) == 62) {  // tile (T>>6) complete
      GU_EPI(c + 16 * (T >> 6));
#pragma unroll
      for (int i = 0; i < 8; ++i)
#pragma unroll
        for (int j = 0; j < 4; ++j) acc[i][j] = z;
    }
  }
  // tail pair (tiles FK-2, FK-1): P1 stages the last half; drain at P4
  {
    LDA(0, 0); LDBS(0, 0, 0);
    PSTG_A(1, 1, FK - 1);
    LGKM8();
    SBAR(); LGKM0(); MFMA16(0, 0); SBAR();
    LDBS(1, 0, 1);
    SBAR(); LGKM0(); MFMA16(0, 1); SBAR();
    LDA(0, 1);
    SBAR(); LGKM0(); MFMA16(1, 1); SBAR();
    VMCNT0();
    SBAR(); MFMA16(1, 0); SBAR();
    LDA(1, 0); LDBS(0, 1, 0);
    LGKM8();
    SBAR(); LGKM0(); MFMA16(0, 0); SBAR();
    LDBS(1, 1, 1);
    SBAR(); LGKM0(); MFMA16(0, 1); SBAR();
    LDA(1, 1);
    SBAR(); LGKM0(); MFMA16(1, 1); SBAR();
    MFMA16(1, 0);
  }
  GU_EPI(c + 16 * (ntiles - 1));
#undef PSTG_A
#undef PSTG_B
#undef LDA
#undef LDBS
#undef MFMA16
#undef GU_EPI
}

// ---------------- down GEMM (frag-once schedule, single tile) --------------
__global__ __launch_bounds__(512, 1) void gemm_down(
    const u16* __restrict__ A, const u16* __restrict__ Bl,
    const u16* __restrict__ Bv, const int* __restrict__ tt,
    float* __restrict__ O) {
  constexpr int KB = 22016;
  constexpr int NK = KB / 128;  // 172
  __shared__ u16 sA[2][2][128][64];
  __shared__ u16 sB[2][2][128][64];

  const int bid = blockIdx.x;
  const int wg = (bid & 7) * 32 + (bid >> 3);
  const int mT = wg & 15;
  const int nT = wg >> 4;

  const int t = threadIdx.x;
  const int lane = t & 63;
  const int rlo = lane & 15;
  const int hi = lane >> 4;
  const int wn = (t >> 6) & 3;
  const int wm = (t >> 8) & 1;

  const int side = tt[mT << 8];
  const u16* B = side ? Bl : Bv;

  const int rowq = t >> 3;
  const int gsw = ((t & 7) ^ (rowq & 7)) << 4;
  const char* srcA = (const char*)A + (size_t)(mT * 256 + rowq) * KB + gsw;
  const char* srcB = (const char*)B + (size_t)(nT * 256 + rowq) * KB + gsw;
  char* ldsA = (char*)&sA[0][0][0][0];
  char* ldsB = (char*)&sB[0][0][0][0];
  const int woff = (t & 448) << 4;

#define STG_A(d, h, kt)                                                        \
  do {                                                                         \
    GLOAD16(srcA + (size_t)((h) * 128) * KB + (kt) * 128,                      \
            ldsA + (d) * 32768 + (h) * 16384 + woff);                          \
    GLOAD16(srcA + (size_t)((h) * 128 + 64) * KB + (kt) * 128,                 \
            ldsA + (d) * 32768 + (h) * 16384 + 8192 + woff);                   \
  } while (0)
#define STG_B(d, h, kt)                                                        \
  do {                                                                         \
    GLOAD16(srcB + (size_t)((h) * 128) * KB + (kt) * 128,                      \
            ldsB + (d) * 32768 + (h) * 16384 + woff);                          \
    GLOAD16(srcB + (size_t)((h) * 128 + 64) * KB + (kt) * 128,                 \
            ldsB + (d) * 32768 + (h) * 16384 + 8192 + woff);                   \
  } while (0)

  const int cxa = (hi ^ (rlo & 7)) << 4;
  const int cxb = ((4 + hi) ^ (rlo & 7)) << 4;
  const int arow = (wm * 64 + rlo) * 128;
  const int brow = (wn * 32 + rlo) * 128;

  s16x8 af[4][2], bf[2][2][2];
  f32x4 acc[8][4];
  const f32x4 z = {0.f, 0.f, 0.f, 0.f};
#pragma unroll
  for (int i = 0; i < 8; ++i)
#pragma unroll
    for (int j = 0; j < 4; ++j) acc[i][j] = z;

#define LDA(d, mh)                                                             \
  do {                                                                         \
    _Pragma("unroll") for (int fi = 0; fi < 4; ++fi) {                         \
      const char* p = ldsA + (d) * 32768 + (mh) * 16384 + arow + fi * 2048;    \
      af[fi][0] = *(const s16x8*)(p + cxa);                                    \
      af[fi][1] = *(const s16x8*)(p + cxb);                                    \
    }                                                                          \
  } while (0)
#define LDBS(bi, d, nh)                                                        \
  do {                                                                         \
    _Pragma("unroll") for (int gi = 0; gi < 2; ++gi) {                         \
      const char* p = ldsB + (d) * 32768 + (nh) * 16384 + brow + gi * 2048;    \
      bf[bi][gi][0] = *(const s16x8*)(p + cxa);                                \
      bf[bi][gi][1] = *(const s16x8*)(p + cxb);                                \
    }                                                                          \
  } while (0)
#define MFMA16(mh, nh)                                                         \
  do {                                                                         \
    __builtin_amdgcn_s_setprio(1);                                             \
    _Pragma("unroll") for (int fi = 0; fi < 4; ++fi)                           \
        _Pragma("unroll") for (int gi = 0; gi < 2; ++gi) {                     \
      acc[(mh)*4 + fi][(nh)*2 + gi] = __builtin_amdgcn_mfma_f32_16x16x32_bf16( \
          af[fi][0], bf[nh][gi][0], acc[(mh)*4 + fi][(nh)*2 + gi], 0, 0, 0);   \
      acc[(mh)*4 + fi][(nh)*2 + gi] = __builtin_amdgcn_mfma_f32_16x16x32_bf16( \
          af[fi][1], bf[nh][gi][1], acc[(mh)*4 + fi][(nh)*2 + gi], 0, 0, 0);   \
    }                                                                          \
    __builtin_amdgcn_s_setprio(0);                                             \
  } while (0)

  STG_A(0, 0, 0); STG_B(0, 0, 0); STG_B(0, 1, 0); STG_A(0, 1, 0);
  STG_A(1, 0, 1); STG_B(1, 0, 1); STG_B(1, 1, 1);
  VMCNT6();
  SBAR();

  for (int T = 0; T < NK - 2; T += 2) {
    LDA(0, 0); LDBS(0, 0, 0);
    STG_A(1, 1, T + 1);
    LGKM8();
    SBAR(); LGKM0(); MFMA16(0, 0); SBAR();
    LDBS(1, 0, 1);
    STG_A(0, 0, T + 2);
    SBAR(); LGKM0(); MFMA16(0, 1); SBAR();
    LDA(0, 1);
    STG_B(0, 0, T + 2);
    SBAR(); LGKM0(); MFMA16(1, 1); SBAR();
    STG_B(0, 1, T + 2);
    VMCNT6();
    SBAR(); MFMA16(1, 0); SBAR();
    LDA(1, 0); LDBS(0, 1, 0);
    STG_A(0, 1, T + 2);
    LGKM8();
    SBAR(); LGKM0(); MFMA16(0, 0); SBAR();
    LDBS(1, 1, 1);
    STG_A(1, 0, T + 3);
    SBAR(); LGKM0(); MFMA16(0, 1); SBAR();
    LDA(1, 1);
    STG_B(1, 0, T + 3);
    SBAR(); LGKM0(); MFMA16(1, 1); SBAR();
    STG_B(1, 1, T + 3);
    VMCNT6();
    SBAR(); MFMA16(1, 0); SBAR();
  }
  {
    LDA(0, 0); LDBS(0, 0, 0);
    STG_A(1, 1, NK - 1);
    LGKM8();
    SBAR(); LGKM0(); MFMA16(0, 0); SBAR();
    LDBS(1, 0, 1);
    SBAR(); LGKM0(); MFMA16(0, 1); SBAR();
    LDA(0, 1);
    SBAR(); LGKM0(); MFMA16(1, 1); SBAR();
    VMCNT0();
    SBAR(); MFMA16(1, 0); SBAR();
    LDA(1, 0); LDBS(0, 1, 0);
    LGKM8();
    SBAR(); LGKM0(); MFMA16(0, 0); SBAR();
    LDBS(1, 1, 1);
    SBAR(); LGKM0(); MFMA16(0, 1); SBAR();
    LDA(1, 1);
    SBAR(); LGKM0(); MFMA16(1, 1); SBAR();
    MFMA16(1, 0);
  }

#pragma unroll
  for (int mh = 0; mh < 2; ++mh)
#pragma unroll
    for (int fi = 0; fi < 4; ++fi) {
      const int row0 = mT * 256 + mh * 128 + wm * 64 + fi * 16 + hi * 4;
#pragma unroll
      for (int nh = 0; nh < 2; ++nh)
#pragma unroll
        for (int gi = 0; gi < 2; ++gi) {
          const int col = nT * 256 + nh * 128 + wn * 32 + gi * 16 + rlo;
          const f32x4 a = acc[mh * 4 + fi][nh * 2 + gi];
#pragma unroll
          for (int r = 0; r < 4; ++r)
            O[(size_t)(row0 + r) * 4096 + col] = a[r];
        }
    }
#undef STG_A
#undef STG_B
#undef LDA
#undef LDBS
#undef MFMA16
}

extern "C" void kernel_launch(void* const* d_in, const int* in_sizes, int n_in,
                              void* d_out, int out_size, void* d_ws, size_t ws_size,
                              hipStream_t stream) {
  (void)in_sizes; (void)n_in; (void)out_size; (void)ws_size;
  const float* x  = (const float*)d_in[0];
  const int*   tt = (const int*)d_in[1];
  const float* lg = (const float*)d_in[2];
  const float* lu = (const float*)d_in[3];
  const float* ld = (const float*)d_in[4];
  const float* vg = (const float*)d_in[5];
  const float* vu = (const float*)d_in[6];
  const float* vd = (const float*)d_in[7];

  u16* ws  = (u16*)d_ws;
  u16* xbf = ws;                        // 4096*4096            = 16,777,216
  u16* GUl = xbf + 16777216;            // 22016*4096           = 90,177,536
  u16* GUv = GUl + 90177536;
  u16* ldT = GUv + 90177536;            // 4096*11008           = 45,088,768
  u16* vdT = ldT + 45088768;
  u16* hbuf = vdT + 45088768;           // 4096*11008
  // total: 332,398,592 u16 = ~665 MB

  prep_kernel<<<dim3(11008, 7), dim3(256), 0, stream>>>(
      lg, lu, vg, vu, ld, vd, x, GUl, GUv, ldT, vdT, xbf);
  gemm_gateup_persist<<<dim3(256), dim3(512), 0, stream>>>(
      xbf, GUl, GUv, tt, hbuf);
  gemm_down<<<dim3(256), dim3(512), 0, stream>>>(hbuf, ldT, vdT, tt, (float*)d_out);
}